// Round 16
// baseline (107.868 us; speedup 1.0000x reference)
//
#include <hip/hip_runtime.h>
#include <cmath>

#define C_DIM 256
#define E_DIM 128
#define S_DIM 4096

typedef __bf16 bf16x8 __attribute__((ext_vector_type(8)));
typedef float  f32x4  __attribute__((ext_vector_type(4)));
typedef short  s16x8  __attribute__((ext_vector_type(8)));
typedef short  s16x4  __attribute__((ext_vector_type(4)));
typedef long long llx2 __attribute__((ext_vector_type(2)));

__device__ __forceinline__ unsigned short f2bf(float f) {
  union { float f; unsigned u; } v; v.f = f;
  unsigned r = v.u + 0x7FFFu + ((v.u >> 16) & 1u);
  return (unsigned short)(r >> 16);
}
__device__ __forceinline__ unsigned short f2bf_tr(float f) {  // truncating
  union { float f; unsigned u; } v; v.f = f;
  return (unsigned short)(v.u >> 16);
}
__device__ __forceinline__ bf16x8 as_bf(s16x8 v) {
  union { s16x8 s; bf16x8 b; } u; u.s = v; return u.b;
}
// 16B register-union bitcasts (compile to nothing)
__device__ __forceinline__ bf16x8 f2b8(f32x4 v) { union { f32x4 f; bf16x8 b; } u; u.f = v; return u.b; }
__device__ __forceinline__ f32x4 b2f8(bf16x8 v) { union { bf16x8 b; f32x4 f; } u; u.b = v; return u.f; }
__device__ __forceinline__ f32x4 s2f8(s16x8 v)  { union { s16x8 s; f32x4 f; } u; u.s = v; return u.f; }
__device__ __forceinline__ s16x8 f2s8(f32x4 v)  { union { f32x4 f; s16x8 s; } u; u.f = v; return u.s; }
__device__ __forceinline__ llx2 f2ll(f32x4 v)   { union { f32x4 f; llx2 l; } u; u.f = v; return u.l; }
__device__ __forceinline__ f32x4 ll2f(llx2 v)   { union { llx2 l; f32x4 f; } u; u.l = v; return u.f; }
// pack 4 floats -> 4 fp8 e4m3 bytes
__device__ __forceinline__ unsigned pk8(float x0, float x1, float x2, float x3) {
  int d = __builtin_amdgcn_cvt_pk_fp8_f32(x0, x1, 0, false);
  d = __builtin_amdgcn_cvt_pk_fp8_f32(x2, x3, d, true);
  return (unsigned)d;
}

#define MFMA16(a, b, c) __builtin_amdgcn_mfma_f32_16x16x32_bf16(a, b, c, 0, 0, 0)

// ---------------------------------------------------------------------------
// Kernel 0: cast weights fp32 -> bf16. [Wth 32768][Wph 32768][Wproj 65536].
// ---------------------------------------------------------------------------
__global__ __launch_bounds__(256) void cast_w_kernel(
    const float* __restrict__ Wth, const float* __restrict__ Wph,
    const float* __restrict__ Wpr, short* __restrict__ Wb) {
  int t = blockIdx.x * 256 + threadIdx.x;
  int i = t * 4;
  const float* src; int j;
  if (i < 32768)      { src = Wth; j = i; }
  else if (i < 65536) { src = Wph; j = i - 32768; }
  else                { src = Wpr; j = i - 65536; }
  float4 v = *(const float4*)(src + j);
  s16x4 o;
  o[0] = (short)f2bf(v.x); o[1] = (short)f2bf(v.y);
  o[2] = (short)f2bf(v.z); o[3] = (short)f2bf(v.w);
  *(s16x4*)(Wb + i) = o;
}

// ---------------------------------------------------------------------------
// Kernel 1 (MFMA): Q[s,e] = qscale * sum_c Wth[e,c] x[c,s]; K likewise.
// Emits fp8 e4m3 copy of x (attention V). grid 512.
// ---------------------------------------------------------------------------
__global__ __launch_bounds__(256) void mix_kernel(
    const float* __restrict__ x, const short* __restrict__ Wb,
    short* __restrict__ Qg, short* __restrict__ Kg,
    unsigned char* __restrict__ Xb8, float qscale) {
  __shared__ short lxT[32 * C_DIM];   // [s][c] bf16, swizzled, 16 KB
  int bid = blockIdx.x;
  int n = bid >> 7, s0 = (bid & 127) * 32;
  int tid = threadIdx.x;
  int wid = tid >> 6, lane = tid & 63, l15 = lane & 15, l4 = lane >> 4;

  { // stage x^T tile (bf16 in LDS) + emit fp8 V copy
    int cp = tid >> 1, su = tid & 1;
    const float* r0 = x + ((size_t)n * C_DIM + 2 * cp) * S_DIM + s0 + su * 16;
    const float* r1 = r0 + S_DIM;
    float a0[16], a1[16];
    #pragma unroll
    for (int j = 0; j < 4; ++j) {
      *(float4*)(a0 + 4 * j) = *(const float4*)(r0 + 4 * j);
      *(float4*)(a1 + 4 * j) = *(const float4*)(r1 + 4 * j);
    }
    unsigned char* xb0 = Xb8 + ((size_t)n * C_DIM + 2 * cp) * S_DIM + s0 + su * 16;
    uint4 w0, w1;
    w0.x = pk8(a0[0], a0[1], a0[2], a0[3]);
    w0.y = pk8(a0[4], a0[5], a0[6], a0[7]);
    w0.z = pk8(a0[8], a0[9], a0[10], a0[11]);
    w0.w = pk8(a0[12], a0[13], a0[14], a0[15]);
    w1.x = pk8(a1[0], a1[1], a1[2], a1[3]);
    w1.y = pk8(a1[4], a1[5], a1[6], a1[7]);
    w1.z = pk8(a1[8], a1[9], a1[10], a1[11]);
    w1.w = pk8(a1[12], a1[13], a1[14], a1[15]);
    *(uint4*)(xb0) = w0;
    *(uint4*)(xb0 + S_DIM) = w1;
    #pragma unroll
    for (int j = 0; j < 16; ++j) {
      int s = su * 16 + j;
      unsigned d = (unsigned)f2bf(a0[j]) | ((unsigned)f2bf(a1[j]) << 16);
      *(unsigned*)((char*)lxT + s * 512 + ((4 * cp) ^ ((s & 7) << 4))) = d;
    }
  }
  __syncthreads();

  const short* Wq = Wb;
  const short* Wk = Wb + 32768;
  const f32x4 fzero = {0.f, 0.f, 0.f, 0.f};
  f32x4 accQ[2][2], accK[2][2];
  #pragma unroll
  for (int a = 0; a < 2; ++a)
    #pragma unroll
    for (int b = 0; b < 2; ++b) { accQ[a][b] = fzero; accK[a][b] = fzero; }

  #pragma unroll 2
  for (int kk = 0; kk < 8; ++kk) {
    bf16x8 bfr[2];
    #pragma unroll
    for (int nf = 0; nf < 2; ++nf) {
      int s = nf * 16 + l15;
      bfr[nf] = *(const bf16x8*)((char*)lxT + s * 512 +
                                 ((kk * 64 + l4 * 16) ^ ((s & 7) << 4)));
    }
    #pragma unroll
    for (int mf = 0; mf < 2; ++mf) {
      int e = wid * 32 + mf * 16 + l15;
      bf16x8 aq = *(const bf16x8*)(Wq + e * C_DIM + kk * 32 + l4 * 8);
      bf16x8 ak = *(const bf16x8*)(Wk + e * C_DIM + kk * 32 + l4 * 8);
      #pragma unroll
      for (int nf = 0; nf < 2; ++nf) {
        accQ[mf][nf] = MFMA16(aq, bfr[nf], accQ[mf][nf]);
        accK[mf][nf] = MFMA16(ak, bfr[nf], accK[mf][nf]);
      }
    }
  }

  #pragma unroll
  for (int mf = 0; mf < 2; ++mf) {
    #pragma unroll
    for (int nf = 0; nf < 2; ++nf) {
      int e = wid * 32 + mf * 16 + l4 * 4;
      int s = s0 + nf * 16 + l15;
      s16x4 pq, pk;
      #pragma unroll
      for (int r = 0; r < 4; ++r) {
        pq[r] = (short)f2bf(accQ[mf][nf][r] * qscale);
        pk[r] = (short)f2bf(accK[mf][nf][r]);
      }
      *(s16x4*)(Qg + ((size_t)n * S_DIM + s) * E_DIM + e) = pq;
      *(s16x4*)(Kg + ((size_t)n * S_DIM + s) * E_DIM + e) = pk;
    }
  }
}

// ---------------------------------------------------------------------------
// Kernel 2: flash attention (r15 skeleton) with RETIMED V PREFETCH:
// V tile t is now issued in window t-1 (was t) -> ~2 windows in flight,
// covering L3-class latency. Same two register buffers (vpreE/vpreO): window
// i consumes vpre[(i-1)&1] then refills the SAME-parity buffer with tile i+1
// (loads issue after the MFMA reads -> WAR-safe). Everything else r15.
// ---------------------------------------------------------------------------

#define QF(qs, ec) f2b8(RA[(qs) * 4 + (ec)])

#define QKT_BODY(B)                                                           \
  {                                                                           \
    const char* kb = (const char*)lK + (B) * 16384;                           \
    char* pw = (char*)lP + (B) * 4096;                                        \
    RB[0] = fzero; RB[1] = fzero; RB[2] = fzero; RB[3] = fzero;               \
    int trow = tq * 16 + l15;                                                 \
    int swz = (trow & 7) << 4;                                                \
    __builtin_amdgcn_s_setprio(1);                                            \
    _Pragma("unroll")                                                         \
    for (int ec = 0; ec < 4; ++ec) {                                          \
      bf16x8 kf = *(const bf16x8*)(kb + trow * 256 + ((ec * 64 + l4 * 16) ^ swz)); \
      _Pragma("unroll")                                                       \
      for (int qs = 0; qs < 4; ++qs)                                          \
        RB[qs] = MFMA16(kf, QF(qs, ec), RB[qs]);                              \
    }                                                                         \
    __builtin_amdgcn_s_setprio(0);                                            \
    int tb1 = tq * 16 + l4 * 4;                                               \
    _Pragma("unroll")                                                         \
    for (int qs = 0; qs < 4; ++qs) {                                          \
      float p0 = __builtin_amdgcn_exp2f(RB[qs][0]);                           \
      float p1 = __builtin_amdgcn_exp2f(RB[qs][1]);                           \
      float p2 = __builtin_amdgcn_exp2f(RB[qs][2]);                           \
      float p3 = __builtin_amdgcn_exp2f(RB[qs][3]);                           \
      lsum[qs] += (p0 + p1) + (p2 + p3);                                      \
      int q = qs * 16 + l15;                                                  \
      *(unsigned*)(pw + q * 64 + (tb1 ^ ((q & 7) << 3))) = pk8(p0, p1, p2, p3); \
    }                                                                         \
  }

#define PV_VISSUE(OFF, TI)                                                    \
  _Pragma("unroll")                                                           \
  for (int j = 0; j < 8; ++j) {                                               \
    long long t_ = *(const long long*)(                                       \
        Vb + (size_t)(cq * 64 + (j & 3) * 16 + l15) * S_DIM +                 \
        (TI) * 64 + (j >> 2) * 32 + l4 * 8);                                  \
    llx2 r_ = f2ll(RA[(OFF) + (j >> 1)]);                                     \
    r_[j & 1] = t_;                                                           \
    RA[(OFF) + (j >> 1)] = ll2f(r_);                                          \
  }

#define PV_KCOMMIT(OFF, B)                                                    \
  {                                                                           \
    char* kw = (char*)lK + (B) * 16384;                                       \
    _Pragma("unroll")                                                         \
    for (int jj = 0; jj < 4; ++jj) {                                          \
      int r = kr + 16 * jj;                                                   \
      *(s16x8*)(kw + r * 256 + ((kc * 16) ^ ((r & 7) << 4))) = f2s8(RB[(OFF) + jj]); \
    }                                                                         \
  }

#define PV_KLOAD(OFF, TI)                                                     \
  _Pragma("unroll")                                                           \
  for (int jj = 0; jj < 4; ++jj)                                              \
    RB[(OFF) + jj] = s2f8(*(const s16x8*)(                                    \
        Kb + (size_t)((TI) * 64 + kr + 16 * jj) * E_DIM + kc * 8));

#define PV_MFMA(OFF, PBUF)                                                    \
  {                                                                           \
    const char* pr = (const char*)lP + (PBUF) * 4096;                         \
    _Pragma("unroll")                                                         \
    for (int kk = 0; kk < 2; ++kk) {                                          \
      long long pf[4];                                                        \
      _Pragma("unroll")                                                       \
      for (int qs = 0; qs < 4; ++qs) {                                        \
        int q = qs * 16 + l15;                                                \
        pf[qs] = *(const long long*)(pr + q * 64 + ((kk * 32 + l4 * 8) ^ ((q & 7) << 3))); \
      }                                                                       \
      __builtin_amdgcn_s_setprio(1);                                          \
      _Pragma("unroll")                                                       \
      for (int ct = 0; ct < 4; ++ct) {                                        \
        long long vf = f2ll(RA[(OFF) + ((kk * 4 + ct) >> 1)])[(kk * 4 + ct) & 1]; \
        _Pragma("unroll")                                                     \
        for (int qs = 0; qs < 4; ++qs)                                        \
          acc[qs][ct] = __builtin_amdgcn_mfma_f32_16x16x32_fp8_fp8(           \
              pf[qs], vf, acc[qs][ct], 0, 0, 0);                              \
      }                                                                       \
      __builtin_amdgcn_s_setprio(0);                                          \
    }                                                                         \
  }

#define RAW_BARRIER()                                                         \
  asm volatile("s_waitcnt lgkmcnt(0)" ::: "memory");                          \
  __builtin_amdgcn_s_barrier();

__global__ __launch_bounds__(512, 2) void attn_kernel(
    const short* __restrict__ Qg, const short* __restrict__ Kg,
    const unsigned char* __restrict__ Xb8, const short* __restrict__ Wpb,
    const float* __restrict__ xg, float* __restrict__ out) {
  __shared__ short lK[2 * 64 * E_DIM];   // 32 KB, dbuf, swizzled [t][e] bf16
  __shared__ char  lP[2 * 64 * 64];      //  8 KB, dbuf, swizzled [q][t] fp8
  __shared__ float lsred[4 * 64];        //  1 KB

  int bid = blockIdx.x;
  int xcd = bid & 7;            // dispatch round-robins XCDs
  int n   = xcd >> 1;           // batch pinned to an XCD pair
  int s0  = (((xcd & 1) << 5) + (bid >> 3)) * 64;

  int tid = threadIdx.x;
  int wid = tid >> 6, lane = tid & 63;
  int l15 = lane & 15, l4 = lane >> 4;

  const short* Kb = Kg + (size_t)n * S_DIM * E_DIM;
  const unsigned char* Vb = Xb8 + (size_t)n * (size_t)C_DIM * S_DIM;

  const f32x4 fzero = {0.f, 0.f, 0.f, 0.f};

  // ------------- role-unioned register file (static indices only) -------
  f32x4 RA[16];             // QKT: qf | PV: vpreE(RA[0..3])/vpreO(RA[4..7])
  f32x4 RB[8];              // QKT: sc(0..3) | PV: kpreE(0..3)/kpreO(4..7)
  float lsum[4];            // QKT only
  f32x4 acc[4][4];          // PV only (AGPR)

  int tq = wid;             // QKT: t-quarter
  int cq = wid - 4;         // PV:  c-quarter
  int idx = tid & 255;
  int kr = idx >> 4, kc = idx & 15;   // K staging (PV waves, 256 threads)

  if (wid < 4) {
    #pragma unroll
    for (int qs = 0; qs < 4; ++qs) {
      const short* qp = Qg + ((size_t)n * S_DIM + s0 + qs * 16 + l15) * E_DIM + l4 * 8;
      #pragma unroll
      for (int ec = 0; ec < 4; ++ec) RA[qs * 4 + ec] = b2f8(*(const bf16x8*)(qp + ec * 32));
    }
    #pragma unroll
    for (int j = 0; j < 4; ++j) lsum[j] = 0.f;
  } else {
    #pragma unroll
    for (int a = 0; a < 4; ++a)
      #pragma unroll
      for (int b = 0; b < 4; ++b) acc[a][b] = fzero;
    // stage K tile 0 into lK buf0 (via RB[0..3], dead after commit)
    PV_KLOAD(0, 0);
    PV_KCOMMIT(0, 0);
    // prefetch K tile 1 -> kpreO(RB[4..7]); V tile 0 -> vpreE(RA[0..3])
    PV_KLOAD(4, 1);
    PV_VISSUE(0, 0);
  }
  RAW_BARRIER();

  // ------------- main: 32 iterations x 2 windows, static buffers -----------
  // V retiming: window i consumes vpre[(i-1)&1] (tile i-1), then refills the
  // SAME-parity buffer with tile i+1 (issued a full window earlier than r15).
  for (int j = 0; j < 32; ++j) {
    int i0 = 2 * j;
    // ---- window i0 (even): QKT on lK buf0 -> lP buf0
    if (wid < 4) {
      QKT_BODY(0);
    } else {
      PV_KCOMMIT(4, 1);                         // kpreO -> K buf1 (tile i0+1)
      if (j > 0)  PV_MFMA(4, 1);                // PV tile i0-1 (vpreO, P buf1)
      PV_VISSUE(4, i0 + 1);                     // vpreO <- V tile i0+1 (cons. i0+2)
      if (j < 31) PV_KLOAD(0, i0 + 2);          // kpreE <- K tile i0+2
    }
    RAW_BARRIER();
    // ---- window i0+1 (odd): QKT on lK buf1 -> lP buf1
    if (wid < 4) {
      QKT_BODY(1);
    } else {
      if (j < 31) PV_KCOMMIT(0, 0);             // kpreE -> K buf0 (tile i0+2)
      PV_MFMA(0, 0);                            // PV tile i0 (vpreE, P buf0)
      if (j < 31) PV_VISSUE(0, i0 + 2);         // vpreE <- V tile i0+2 (cons. i0+3)
      if (j < 31) PV_KLOAD(4, i0 + 3);          // kpreO <- K tile i0+3
    }
    RAW_BARRIER();
  }
  // final window 64: PV on tile 63 (P in buf1, V in vpreO, issued window 62)
  if (wid >= 4) {
    PV_MFMA(4, 1);
  }

  // ---------------- epilogue: normalize y into LDS ----------------
  if (wid < 4) {
    #pragma unroll
    for (int qs = 0; qs < 4; ++qs) {
      float v = lsum[qs];
      v += __shfl_xor(v, 16);
      v += __shfl_xor(v, 32);
      if (lane < 16) lsred[tq * 64 + qs * 16 + l15] = v;
    }
  }
  __syncthreads();

  char* yst = (char*)lK;   // reuse 32 KB as [64 q][256 c] bf16, swizzled
  if (wid >= 4) {
    #pragma unroll
    for (int qs = 0; qs < 4; ++qs) {
      #pragma unroll
      for (int r = 0; r < 4; ++r) {
        int q = qs * 16 + l4 * 4 + r;
        float tot = lsred[q] + lsred[64 + q] + lsred[128 + q] + lsred[192 + q];
        float rl = 1.0f / tot;
        #pragma unroll
        for (int ct = 0; ct < 4; ++ct) {
          int c = cq * 64 + ct * 16 + l15;
          *(unsigned short*)(yst + q * 512 + ((c * 2) ^ ((q & 7) << 4))) =
              f2bf_tr(acc[qs][ct][r] * rl);
        }
      }
    }
  }
  __syncthreads();

  // ---------------- fused proj: out[o, s0+q] = x + sum_c Wp[o,c] y[q,c] ----
  {
    f32x4 pacc[4][2];
    #pragma unroll
    for (int a = 0; a < 4; ++a)
      #pragma unroll
      for (int b = 0; b < 2; ++b) pacc[a][b] = fzero;

    #pragma unroll 2
    for (int kk = 0; kk < 8; ++kk) {
      bf16x8 af[4];
      #pragma unroll
      for (int mf = 0; mf < 4; ++mf) {
        int q = mf * 16 + l15;
        af[mf] = *(const bf16x8*)(yst + q * 512 + ((kk * 64 + l4 * 16) ^ ((q & 7) << 4)));
      }
      #pragma unroll
      for (int nf = 0; nf < 2; ++nf) {
        int o = wid * 32 + nf * 16 + l15;
        bf16x8 bfr = *(const bf16x8*)(Wpb + o * C_DIM + kk * 32 + l4 * 8);
        #pragma unroll
        for (int mf = 0; mf < 4; ++mf)
          pacc[mf][nf] = MFMA16(af[mf], bfr, pacc[mf][nf]);
      }
    }

    #pragma unroll
    for (int mf = 0; mf < 4; ++mf) {
      #pragma unroll
      for (int nf = 0; nf < 2; ++nf) {
        int o = wid * 32 + nf * 16 + l15;
        size_t idx2 = ((size_t)n * C_DIM + o) * (size_t)S_DIM + s0 + mf * 16 + l4 * 4;
        float4 xv = *(const float4*)(xg + idx2);
        float4 r;
        r.x = xv.x + pacc[mf][nf][0];
        r.y = xv.y + pacc[mf][nf][1];
        r.z = xv.z + pacc[mf][nf][2];
        r.w = xv.w + pacc[mf][nf][3];
        *(float4*)(out + idx2) = r;
      }
    }
  }
}

// ---------------------------------------------------------------------------
extern "C" void kernel_launch(void* const* d_in, const int* in_sizes, int n_in,
                              void* d_out, int out_size, void* d_ws, size_t ws_size,
                              hipStream_t stream) {
  const float* x   = (const float*)d_in[0];
  const float* Wth = (const float*)d_in[1];
  const float* Wph = (const float*)d_in[2];
  const float* Wpr = (const float*)d_in[3];
  float* out = (float*)d_out;

  short* q_ws  = (short*)d_ws;                              // 4 MB  [N,S,E] bf16
  short* k_ws  = q_ws + (size_t)4 * S_DIM * E_DIM;          // 4 MB  [N,S,E] bf16
  unsigned char* xb8_ws = (unsigned char*)(k_ws + (size_t)4 * S_DIM * E_DIM); // 4 MB [N,C,S] fp8
  short* wb_ws = (short*)(xb8_ws + (size_t)4 * C_DIM * S_DIM);  // 256 KB bf16 weights

  float qscale = 1.4426950408889634f / sqrtf(128.0f);       // log2(e)/sqrt(E)

  cast_w_kernel<<<128, 256, 0, stream>>>(Wth, Wph, Wpr, wb_ws);
  mix_kernel<<<512, 256, 0, stream>>>(x, wb_ws, q_ws, k_ws, xb8_ws, qscale);
  attn_kernel<<<256, 512, 0, stream>>>(q_ws, k_ws, xb8_ws, wb_ws + 65536, x, out);
}

// Round 17
// 104.898 us; speedup vs baseline: 1.0283x; 1.0283x over previous
//
#include <hip/hip_runtime.h>
#include <cmath>

#define C_DIM 256
#define E_DIM 128
#define S_DIM 4096

typedef __bf16 bf16x8 __attribute__((ext_vector_type(8)));
typedef float  f32x4  __attribute__((ext_vector_type(4)));
typedef short  s16x8  __attribute__((ext_vector_type(8)));
typedef short  s16x4  __attribute__((ext_vector_type(4)));
typedef long long llx2 __attribute__((ext_vector_type(2)));

__device__ __forceinline__ unsigned short f2bf(float f) {
  union { float f; unsigned u; } v; v.f = f;
  unsigned r = v.u + 0x7FFFu + ((v.u >> 16) & 1u);
  return (unsigned short)(r >> 16);
}
__device__ __forceinline__ unsigned short f2bf_tr(float f) {  // truncating
  union { float f; unsigned u; } v; v.f = f;
  return (unsigned short)(v.u >> 16);
}
__device__ __forceinline__ bf16x8 as_bf(s16x8 v) {
  union { s16x8 s; bf16x8 b; } u; u.s = v; return u.b;
}
// 16B register-union bitcasts (compile to nothing)
__device__ __forceinline__ bf16x8 f2b8(f32x4 v) { union { f32x4 f; bf16x8 b; } u; u.f = v; return u.b; }
__device__ __forceinline__ f32x4 b2f8(bf16x8 v) { union { bf16x8 b; f32x4 f; } u; u.b = v; return u.f; }
__device__ __forceinline__ f32x4 s2f8(s16x8 v)  { union { s16x8 s; f32x4 f; } u; u.s = v; return u.f; }
__device__ __forceinline__ s16x8 f2s8(f32x4 v)  { union { f32x4 f; s16x8 s; } u; u.f = v; return u.s; }
__device__ __forceinline__ llx2 f2ll(f32x4 v)   { union { f32x4 f; llx2 l; } u; u.f = v; return u.l; }
__device__ __forceinline__ f32x4 ll2f(llx2 v)   { union { llx2 l; f32x4 f; } u; u.l = v; return u.f; }
// pack 4 floats -> 4 fp8 e4m3 bytes
__device__ __forceinline__ unsigned pk8(float x0, float x1, float x2, float x3) {
  int d = __builtin_amdgcn_cvt_pk_fp8_f32(x0, x1, 0, false);
  d = __builtin_amdgcn_cvt_pk_fp8_f32(x2, x3, d, true);
  return (unsigned)d;
}

#define MFMA16(a, b, c) __builtin_amdgcn_mfma_f32_16x16x32_bf16(a, b, c, 0, 0, 0)

// ---------------------------------------------------------------------------
// Kernel 0: cast weights fp32 -> bf16. [Wth 32768][Wph 32768][Wproj 65536].
// ---------------------------------------------------------------------------
__global__ __launch_bounds__(256) void cast_w_kernel(
    const float* __restrict__ Wth, const float* __restrict__ Wph,
    const float* __restrict__ Wpr, short* __restrict__ Wb) {
  int t = blockIdx.x * 256 + threadIdx.x;
  int i = t * 4;
  const float* src; int j;
  if (i < 32768)      { src = Wth; j = i; }
  else if (i < 65536) { src = Wph; j = i - 32768; }
  else                { src = Wpr; j = i - 65536; }
  float4 v = *(const float4*)(src + j);
  s16x4 o;
  o[0] = (short)f2bf(v.x); o[1] = (short)f2bf(v.y);
  o[2] = (short)f2bf(v.z); o[3] = (short)f2bf(v.w);
  *(s16x4*)(Wb + i) = o;
}

// ---------------------------------------------------------------------------
// Kernel 1 (MFMA): Q[s,e] = qscale * sum_c Wth[e,c] x[c,s]; K likewise.
// Emits fp8 e4m3 copy of x (attention V). grid 512.
// ---------------------------------------------------------------------------
__global__ __launch_bounds__(256) void mix_kernel(
    const float* __restrict__ x, const short* __restrict__ Wb,
    short* __restrict__ Qg, short* __restrict__ Kg,
    unsigned char* __restrict__ Xb8, float qscale) {
  __shared__ short lxT[32 * C_DIM];   // [s][c] bf16, swizzled, 16 KB
  int bid = blockIdx.x;
  int n = bid >> 7, s0 = (bid & 127) * 32;
  int tid = threadIdx.x;
  int wid = tid >> 6, lane = tid & 63, l15 = lane & 15, l4 = lane >> 4;

  { // stage x^T tile (bf16 in LDS) + emit fp8 V copy
    int cp = tid >> 1, su = tid & 1;
    const float* r0 = x + ((size_t)n * C_DIM + 2 * cp) * S_DIM + s0 + su * 16;
    const float* r1 = r0 + S_DIM;
    float a0[16], a1[16];
    #pragma unroll
    for (int j = 0; j < 4; ++j) {
      *(float4*)(a0 + 4 * j) = *(const float4*)(r0 + 4 * j);
      *(float4*)(a1 + 4 * j) = *(const float4*)(r1 + 4 * j);
    }
    unsigned char* xb0 = Xb8 + ((size_t)n * C_DIM + 2 * cp) * S_DIM + s0 + su * 16;
    uint4 w0, w1;
    w0.x = pk8(a0[0], a0[1], a0[2], a0[3]);
    w0.y = pk8(a0[4], a0[5], a0[6], a0[7]);
    w0.z = pk8(a0[8], a0[9], a0[10], a0[11]);
    w0.w = pk8(a0[12], a0[13], a0[14], a0[15]);
    w1.x = pk8(a1[0], a1[1], a1[2], a1[3]);
    w1.y = pk8(a1[4], a1[5], a1[6], a1[7]);
    w1.z = pk8(a1[8], a1[9], a1[10], a1[11]);
    w1.w = pk8(a1[12], a1[13], a1[14], a1[15]);
    *(uint4*)(xb0) = w0;
    *(uint4*)(xb0 + S_DIM) = w1;
    #pragma unroll
    for (int j = 0; j < 16; ++j) {
      int s = su * 16 + j;
      unsigned d = (unsigned)f2bf(a0[j]) | ((unsigned)f2bf(a1[j]) << 16);
      *(unsigned*)((char*)lxT + s * 512 + ((4 * cp) ^ ((s & 7) << 4))) = d;
    }
  }
  __syncthreads();

  const short* Wq = Wb;
  const short* Wk = Wb + 32768;
  const f32x4 fzero = {0.f, 0.f, 0.f, 0.f};
  f32x4 accQ[2][2], accK[2][2];
  #pragma unroll
  for (int a = 0; a < 2; ++a)
    #pragma unroll
    for (int b = 0; b < 2; ++b) { accQ[a][b] = fzero; accK[a][b] = fzero; }

  #pragma unroll 2
  for (int kk = 0; kk < 8; ++kk) {
    bf16x8 bfr[2];
    #pragma unroll
    for (int nf = 0; nf < 2; ++nf) {
      int s = nf * 16 + l15;
      bfr[nf] = *(const bf16x8*)((char*)lxT + s * 512 +
                                 ((kk * 64 + l4 * 16) ^ ((s & 7) << 4)));
    }
    #pragma unroll
    for (int mf = 0; mf < 2; ++mf) {
      int e = wid * 32 + mf * 16 + l15;
      bf16x8 aq = *(const bf16x8*)(Wq + e * C_DIM + kk * 32 + l4 * 8);
      bf16x8 ak = *(const bf16x8*)(Wk + e * C_DIM + kk * 32 + l4 * 8);
      #pragma unroll
      for (int nf = 0; nf < 2; ++nf) {
        accQ[mf][nf] = MFMA16(aq, bfr[nf], accQ[mf][nf]);
        accK[mf][nf] = MFMA16(ak, bfr[nf], accK[mf][nf]);
      }
    }
  }

  #pragma unroll
  for (int mf = 0; mf < 2; ++mf) {
    #pragma unroll
    for (int nf = 0; nf < 2; ++nf) {
      int e = wid * 32 + mf * 16 + l4 * 4;
      int s = s0 + nf * 16 + l15;
      s16x4 pq, pk;
      #pragma unroll
      for (int r = 0; r < 4; ++r) {
        pq[r] = (short)f2bf(accQ[mf][nf][r] * qscale);
        pk[r] = (short)f2bf(accK[mf][nf][r]);
      }
      *(s16x4*)(Qg + ((size_t)n * S_DIM + s) * E_DIM + e) = pq;
      *(s16x4*)(Kg + ((size_t)n * S_DIM + s) * E_DIM + e) = pk;
    }
  }
}

// ---------------------------------------------------------------------------
// Kernel 2: flash attention (r15 final form): fp8 V and fp8 P, bf16 QK^T,
// producer-consumer wave split, RAW lgkm-only barriers, fused proj epilogue.
// Register unions: RA[16] = QKT qf | PV vpreE(RA[0..3])/vpreO(RA[4..7]);
//                  RB[8]  = QKT sc(0..3) | PV kpreE(0..3)/kpreO(4..7)
// ---------------------------------------------------------------------------

#define QF(qs, ec) f2b8(RA[(qs) * 4 + (ec)])

#define QKT_BODY(B)                                                           \
  {                                                                           \
    const char* kb = (const char*)lK + (B) * 16384;                           \
    char* pw = (char*)lP + (B) * 4096;                                        \
    RB[0] = fzero; RB[1] = fzero; RB[2] = fzero; RB[3] = fzero;               \
    int trow = tq * 16 + l15;                                                 \
    int swz = (trow & 7) << 4;                                                \
    __builtin_amdgcn_s_setprio(1);                                            \
    _Pragma("unroll")                                                         \
    for (int ec = 0; ec < 4; ++ec) {                                          \
      bf16x8 kf = *(const bf16x8*)(kb + trow * 256 + ((ec * 64 + l4 * 16) ^ swz)); \
      _Pragma("unroll")                                                       \
      for (int qs = 0; qs < 4; ++qs)                                          \
        RB[qs] = MFMA16(kf, QF(qs, ec), RB[qs]);                              \
    }                                                                         \
    __builtin_amdgcn_s_setprio(0);                                            \
    int tb1 = tq * 16 + l4 * 4;                                               \
    _Pragma("unroll")                                                         \
    for (int qs = 0; qs < 4; ++qs) {                                          \
      float p0 = __builtin_amdgcn_exp2f(RB[qs][0]);                           \
      float p1 = __builtin_amdgcn_exp2f(RB[qs][1]);                           \
      float p2 = __builtin_amdgcn_exp2f(RB[qs][2]);                           \
      float p3 = __builtin_amdgcn_exp2f(RB[qs][3]);                           \
      lsum[qs] += (p0 + p1) + (p2 + p3);                                      \
      int q = qs * 16 + l15;                                                  \
      *(unsigned*)(pw + q * 64 + (tb1 ^ ((q & 7) << 3))) = pk8(p0, p1, p2, p3); \
    }                                                                         \
  }

#define PV_VISSUE(OFF, TI)                                                    \
  _Pragma("unroll")                                                           \
  for (int j = 0; j < 8; ++j) {                                               \
    long long t_ = *(const long long*)(                                       \
        Vb + (size_t)(cq * 64 + (j & 3) * 16 + l15) * S_DIM +                 \
        (TI) * 64 + (j >> 2) * 32 + l4 * 8);                                  \
    llx2 r_ = f2ll(RA[(OFF) + (j >> 1)]);                                     \
    r_[j & 1] = t_;                                                           \
    RA[(OFF) + (j >> 1)] = ll2f(r_);                                          \
  }

#define PV_KCOMMIT(OFF, B)                                                    \
  {                                                                           \
    char* kw = (char*)lK + (B) * 16384;                                       \
    _Pragma("unroll")                                                         \
    for (int jj = 0; jj < 4; ++jj) {                                          \
      int r = kr + 16 * jj;                                                   \
      *(s16x8*)(kw + r * 256 + ((kc * 16) ^ ((r & 7) << 4))) = f2s8(RB[(OFF) + jj]); \
    }                                                                         \
  }

#define PV_KLOAD(OFF, TI)                                                     \
  _Pragma("unroll")                                                           \
  for (int jj = 0; jj < 4; ++jj)                                              \
    RB[(OFF) + jj] = s2f8(*(const s16x8*)(                                    \
        Kb + (size_t)((TI) * 64 + kr + 16 * jj) * E_DIM + kc * 8));

#define PV_MFMA(OFF, PBUF)                                                    \
  {                                                                           \
    const char* pr = (const char*)lP + (PBUF) * 4096;                         \
    _Pragma("unroll")                                                         \
    for (int kk = 0; kk < 2; ++kk) {                                          \
      long long pf[4];                                                        \
      _Pragma("unroll")                                                       \
      for (int qs = 0; qs < 4; ++qs) {                                        \
        int q = qs * 16 + l15;                                                \
        pf[qs] = *(const long long*)(pr + q * 64 + ((kk * 32 + l4 * 8) ^ ((q & 7) << 3))); \
      }                                                                       \
      __builtin_amdgcn_s_setprio(1);                                          \
      _Pragma("unroll")                                                       \
      for (int ct = 0; ct < 4; ++ct) {                                        \
        long long vf = f2ll(RA[(OFF) + ((kk * 4 + ct) >> 1)])[(kk * 4 + ct) & 1]; \
        _Pragma("unroll")                                                     \
        for (int qs = 0; qs < 4; ++qs)                                        \
          acc[qs][ct] = __builtin_amdgcn_mfma_f32_16x16x32_fp8_fp8(           \
              pf[qs], vf, acc[qs][ct], 0, 0, 0);                              \
      }                                                                       \
      __builtin_amdgcn_s_setprio(0);                                          \
    }                                                                         \
  }

#define RAW_BARRIER()                                                         \
  asm volatile("s_waitcnt lgkmcnt(0)" ::: "memory");                          \
  __builtin_amdgcn_s_barrier();

__global__ __launch_bounds__(512, 2) void attn_kernel(
    const short* __restrict__ Qg, const short* __restrict__ Kg,
    const unsigned char* __restrict__ Xb8, const short* __restrict__ Wpb,
    const float* __restrict__ xg, float* __restrict__ out) {
  __shared__ short lK[2 * 64 * E_DIM];   // 32 KB, dbuf, swizzled [t][e] bf16
  __shared__ char  lP[2 * 64 * 64];      //  8 KB, dbuf, swizzled [q][t] fp8
  __shared__ float lsred[4 * 64];        //  1 KB

  int bid = blockIdx.x;
  int xcd = bid & 7;            // dispatch round-robins XCDs
  int n   = xcd >> 1;           // batch pinned to an XCD pair
  int s0  = (((xcd & 1) << 5) + (bid >> 3)) * 64;

  int tid = threadIdx.x;
  int wid = tid >> 6, lane = tid & 63;
  int l15 = lane & 15, l4 = lane >> 4;

  const short* Kb = Kg + (size_t)n * S_DIM * E_DIM;
  const unsigned char* Vb = Xb8 + (size_t)n * (size_t)C_DIM * S_DIM;

  const f32x4 fzero = {0.f, 0.f, 0.f, 0.f};

  // ------------- role-unioned register file (static indices only) -------
  f32x4 RA[16];             // QKT: qf | PV: vpreE(RA[0..3])/vpreO(RA[4..7])
  f32x4 RB[8];              // QKT: sc(0..3) | PV: kpreE(0..3)/kpreO(4..7)
  float lsum[4];            // QKT only
  f32x4 acc[4][4];          // PV only (AGPR)

  int tq = wid;             // QKT: t-quarter
  int cq = wid - 4;         // PV:  c-quarter
  int idx = tid & 255;
  int kr = idx >> 4, kc = idx & 15;   // K staging (PV waves, 256 threads)

  if (wid < 4) {
    #pragma unroll
    for (int qs = 0; qs < 4; ++qs) {
      const short* qp = Qg + ((size_t)n * S_DIM + s0 + qs * 16 + l15) * E_DIM + l4 * 8;
      #pragma unroll
      for (int ec = 0; ec < 4; ++ec) RA[qs * 4 + ec] = b2f8(*(const bf16x8*)(qp + ec * 32));
    }
    #pragma unroll
    for (int j = 0; j < 4; ++j) lsum[j] = 0.f;
  } else {
    #pragma unroll
    for (int a = 0; a < 4; ++a)
      #pragma unroll
      for (int b = 0; b < 4; ++b) acc[a][b] = fzero;
    // stage K tile 0 into lK buf0 (via RB[0..3], dead after commit)
    PV_KLOAD(0, 0);
    PV_KCOMMIT(0, 0);
    // prefetch K tile 1 -> kpreO(RB[4..7]); V tile 0 -> vpreE(RA[0..3])
    PV_KLOAD(4, 1);
    PV_VISSUE(0, 0);
  }
  RAW_BARRIER();

  // ------------- main: 32 iterations x 2 windows, static buffers -----------
  for (int j = 0; j < 32; ++j) {
    int i0 = 2 * j;
    // ---- window i0 (even): QKT on lK buf0 -> lP buf0
    if (wid < 4) {
      QKT_BODY(0);
    } else {
      if (j > 0)  PV_VISSUE(0, i0);            // vpreE <- V tile i0 (cons. i0+1)
      PV_KCOMMIT(4, 1);                         // kpreO -> K buf1 (tile i0+1)
      if (j > 0)  PV_MFMA(4, 1);                // PV tile i0-1 (vpreO, P buf1)
      if (j < 31) PV_KLOAD(0, i0 + 2);          // kpreE <- K tile i0+2
    }
    RAW_BARRIER();
    // ---- window i0+1 (odd): QKT on lK buf1 -> lP buf1
    if (wid < 4) {
      QKT_BODY(1);
    } else {
      PV_VISSUE(4, i0 + 1);                     // vpreO <- V tile i0+1 (cons. i0+2)
      if (j < 31) PV_KCOMMIT(0, 0);             // kpreE -> K buf0 (tile i0+2)
      PV_MFMA(0, 0);                            // PV tile i0 (vpreE, P buf0)
      if (j < 31) PV_KLOAD(4, i0 + 3);          // kpreO <- K tile i0+3
    }
    RAW_BARRIER();
  }
  // final window 64: PV on tile 63 (P in buf1, V in vpreO)
  if (wid >= 4) {
    PV_MFMA(4, 1);
  }

  // ---------------- epilogue: normalize y into LDS ----------------
  if (wid < 4) {
    #pragma unroll
    for (int qs = 0; qs < 4; ++qs) {
      float v = lsum[qs];
      v += __shfl_xor(v, 16);
      v += __shfl_xor(v, 32);
      if (lane < 16) lsred[tq * 64 + qs * 16 + l15] = v;
    }
  }
  __syncthreads();

  char* yst = (char*)lK;   // reuse 32 KB as [64 q][256 c] bf16, swizzled
  if (wid >= 4) {
    #pragma unroll
    for (int qs = 0; qs < 4; ++qs) {
      #pragma unroll
      for (int r = 0; r < 4; ++r) {
        int q = qs * 16 + l4 * 4 + r;
        float tot = lsred[q] + lsred[64 + q] + lsred[128 + q] + lsred[192 + q];
        float rl = 1.0f / tot;
        #pragma unroll
        for (int ct = 0; ct < 4; ++ct) {
          int c = cq * 64 + ct * 16 + l15;
          *(unsigned short*)(yst + q * 512 + ((c * 2) ^ ((q & 7) << 4))) =
              f2bf_tr(acc[qs][ct][r] * rl);
        }
      }
    }
  }
  __syncthreads();

  // ---------------- fused proj: out[o, s0+q] = x + sum_c Wp[o,c] y[q,c] ----
  {
    f32x4 pacc[4][2];
    #pragma unroll
    for (int a = 0; a < 4; ++a)
      #pragma unroll
      for (int b = 0; b < 2; ++b) pacc[a][b] = fzero;

    #pragma unroll 2
    for (int kk = 0; kk < 8; ++kk) {
      bf16x8 af[4];
      #pragma unroll
      for (int mf = 0; mf < 4; ++mf) {
        int q = mf * 16 + l15;
        af[mf] = *(const bf16x8*)(yst + q * 512 + ((kk * 64 + l4 * 16) ^ ((q & 7) << 4)));
      }
      #pragma unroll
      for (int nf = 0; nf < 2; ++nf) {
        int o = wid * 32 + nf * 16 + l15;
        bf16x8 bfr = *(const bf16x8*)(Wpb + o * C_DIM + kk * 32 + l4 * 8);
        #pragma unroll
        for (int mf = 0; mf < 4; ++mf)
          pacc[mf][nf] = MFMA16(af[mf], bfr, pacc[mf][nf]);
      }
    }

    #pragma unroll
    for (int mf = 0; mf < 4; ++mf) {
      #pragma unroll
      for (int nf = 0; nf < 2; ++nf) {
        int o = wid * 32 + nf * 16 + l15;
        size_t idx2 = ((size_t)n * C_DIM + o) * (size_t)S_DIM + s0 + mf * 16 + l4 * 4;
        float4 xv = *(const float4*)(xg + idx2);
        float4 r;
        r.x = xv.x + pacc[mf][nf][0];
        r.y = xv.y + pacc[mf][nf][1];
        r.z = xv.z + pacc[mf][nf][2];
        r.w = xv.w + pacc[mf][nf][3];
        *(float4*)(out + idx2) = r;
      }
    }
  }
}

// ---------------------------------------------------------------------------
extern "C" void kernel_launch(void* const* d_in, const int* in_sizes, int n_in,
                              void* d_out, int out_size, void* d_ws, size_t ws_size,
                              hipStream_t stream) {
  const float* x   = (const float*)d_in[0];
  const float* Wth = (const float*)d_in[1];
  const float* Wph = (const float*)d_in[2];
  const float* Wpr = (const float*)d_in[3];
  float* out = (float*)d_out;

  short* q_ws  = (short*)d_ws;                              // 4 MB  [N,S,E] bf16
  short* k_ws  = q_ws + (size_t)4 * S_DIM * E_DIM;          // 4 MB  [N,S,E] bf16
  unsigned char* xb8_ws = (unsigned char*)(k_ws + (size_t)4 * S_DIM * E_DIM); // 4 MB [N,C,S] fp8
  short* wb_ws = (short*)(xb8_ws + (size_t)4 * C_DIM * S_DIM);  // 256 KB bf16 weights

  float qscale = 1.4426950408889634f / sqrtf(128.0f);       // log2(e)/sqrt(E)

  cast_w_kernel<<<128, 256, 0, stream>>>(Wth, Wph, Wpr, wb_ws);
  mix_kernel<<<512, 256, 0, stream>>>(x, wb_ws, q_ws, k_ws, xb8_ws, qscale);
  attn_kernel<<<256, 512, 0, stream>>>(q_ws, k_ws, xb8_ws, wb_ws + 65536, x, out);
}